// Round 1
// baseline (73.315 us; speedup 1.0000x reference)
//
#include <hip/hip_runtime.h>
#include <math.h>

// Output flat layout (harness reads whole d_out as float32):
//   [0 .. 3L)        input_tensor (L,3): X, Y, one_hot
//   [3L .. 3L+2B)    closest_points (B,2)
//   [3L+2B .. +B)    min_index written as float values
//
// R15: fused filter+reduce. Counters showed the 42 us harness ws-poison
// fill dominates the timed window; our controllable budget is ~30 us.
// The old argmin_block kernel (dependent cellcnt->prefix->cellbuf chain +
// 8-step LDS reduce) existed only to reduce ~138 candidates/receiver.
// New structure: B==256==blockDim -> thread t holds receiver t in regs.
// Filter blocks compact bitmap-passing points into an LDS queue, each
// thread sweeps the queue (LDS broadcast) against its receiver and does a
// gated u64 atomicMin of packed (d2_bits<<32 | idx) -> lex (d2,idx) min
// == numpy first-occurrence argmin. ~12k atomics over 256 addresses.
//
// Exactness: d2 = fp32 sub/mul/mul/add exactly as numpy (no FMA via
// __fmul_rn/__fadd_rn). Certificate: any point within Euclid CELLW of
// receiver r is Chebyshev<=1 from r's cell -> passes the bitmap -> swept
// against r. Points failing the bitmap have d2 >= W2 > GATE for every
// receiver. If the final key's d2 < GATE, every point with smaller key
// was swept, so the key is the global lex-min. Workspace-poison safety:
// 0xAAAAAAAAAAAAAAAA > any real key (d2>=0 -> top bit 0), so no init
// needed; finalize validates (idx in range, recomputed d2 bit-equal,
// d2 < GATE) and falls back to exact in-block brute force on any
// anomaly. A validated garbage key is itself a genuine (point,distance)
// pair, and the true min key is <= any genuine pair's key, so the
// result is exact under ANY workspace state.

#define G      256
#define GG     (G * G)
#define BMW    (GG / 32)              // bitmap words: 2048 (8 KB LDS)
#define CELLW  (10.0f / (float)G)     // 0.0390625
#define W2     (CELLW * CELLW)        // 0.00152587890625
#define GATE   (0.98f * W2)
#define INVW   ((float)G / 10.0f)     // 25.6
#define QCAP   1024                   // max passing points per block tile
#define NCHUNK 1024                   // brute-force fallback path

__device__ __forceinline__ int clampi(int v, int lo, int hi) {
    return min(max(v, lo), hi);
}

__device__ __forceinline__ int cell_of(float x, float y) {
    int cx = clampi((int)(x * INVW), 0, G - 1);
    int cy = clampi((int)(y * INVW), 0, G - 1);
    return cy * G + cx;
}

// ---------------- candidate path ----------------

// One block-tile of 1024 points per block (256 threads x 4 points).
// Copy to out, classify vs LDS bitmap, compact passers into LDS queue,
// sweep queue: thread t <-> receiver t, gated u64 atomicMin into wskey.
__global__ void fused_filter_kernel(const float4* __restrict__ mesh4,
                                    float4* __restrict__ out4,
                                    const float* __restrict__ recv,
                                    unsigned long long* __restrict__ wskey,
                                    int L, int B, int nt4) {
    __shared__ unsigned sbm[BMW];     // 8 KB stamped-cell bitmap
    __shared__ int qn;
    __shared__ float qx[QCAP];        // 4 KB
    __shared__ float qy[QCAP];        // 4 KB
    __shared__ int   qi[QCAP];        // 4 KB

    const int tt = threadIdx.x;
    for (int i = tt; i < BMW; i += 256) sbm[i] = 0u;
    if (tt == 0) qn = 0;

    // receiver t lives in thread t's registers
    float rx = 0.0f, ry = 0.0f;
    const bool has_r = (tt < B);
    if (has_r) {
        rx = recv[3 * tt + 0];
        ry = recv[3 * tt + 1];
    }
    __syncthreads();                  // bitmap zeroed, qn=0 visible

    if (has_r) {
        int cx = clampi((int)(rx * INVW), 0, G - 1);
        int cy = clampi((int)(ry * INVW), 0, G - 1);
        for (int uy = max(cy - 1, 0); uy <= min(cy + 1, G - 1); ++uy)
            for (int ux = max(cx - 1, 0); ux <= min(cx + 1, G - 1); ++ux) {
                int c = uy * G + ux;
                atomicOr(&sbm[c >> 5], 1u << (c & 31));
            }
    }
    __syncthreads();                  // bitmap ready

    const int t = blockIdx.x * 256 + tt;
    if (t < nt4) {
        const int p0 = t * 4;
        float xs[4], ys[4];
        if (p0 + 3 < L) {
            float4 a = mesh4[2 * t];       // x0 y0 x1 y1
            float4 b = mesh4[2 * t + 1];   // x2 y2 x3 y3
            out4[3 * t + 0] = make_float4(a.x, a.y, 0.0f, a.z);
            out4[3 * t + 1] = make_float4(a.w, 0.0f, b.x, b.y);
            out4[3 * t + 2] = make_float4(0.0f, b.z, b.w, 0.0f);
            xs[0] = a.x; ys[0] = a.y; xs[1] = a.z; ys[1] = a.w;
            xs[2] = b.x; ys[2] = b.y; xs[3] = b.z; ys[3] = b.w;
        } else {
            const float2* mesh = (const float2*)mesh4;
            float* out0 = (float*)out4;
            for (int k = 0; k < 4; ++k) {
                int p = p0 + k;
                if (p >= L) { xs[k] = -100.0f; ys[k] = -100.0f; continue; }
                float2 pt = mesh[p];
                out0[3 * (size_t)p + 0] = pt.x;
                out0[3 * (size_t)p + 1] = pt.y;
                out0[3 * (size_t)p + 2] = 0.0f;
                xs[k] = pt.x; ys[k] = pt.y;
            }
        }
        #pragma unroll
        for (int k = 0; k < 4; ++k) {
            int p = p0 + k;
            if (p >= L) continue;
            int c = cell_of(xs[k], ys[k]);
            if ((sbm[c >> 5] >> (c & 31)) & 1u) {
                int q = atomicAdd(&qn, 1);     // q < QCAP by construction
                qx[q] = xs[k]; qy[q] = ys[k]; qi[q] = p;
            }
        }
    }
    __syncthreads();                  // queue complete

    const int Qn = qn;
    if (has_r) {
        for (int e = 0; e < Qn; ++e) {        // LDS broadcast reads
            float dx = qx[e] - rx;
            float dy = qy[e] - ry;
            float d2 = __fadd_rn(__fmul_rn(dx, dx), __fmul_rn(dy, dy));
            if (d2 < GATE) {
                unsigned long long key =
                    ((unsigned long long)__float_as_uint(d2) << 32) |
                    (unsigned long long)(unsigned)qi[e];
                atomicMin(&wskey[tt], key);
            }
        }
    }
}

// One block per receiver: validate packed key; exact brute force backstop.
__global__ void finalize_kernel(const float2* __restrict__ mesh,
                                const float* __restrict__ recv,
                                const unsigned long long* __restrict__ wskey,
                                float* __restrict__ out0,
                                float* __restrict__ out1,
                                float* __restrict__ out2,
                                int L, int B) {
    const int r = blockIdx.x;
    const int t = threadIdx.x;
    if (r >= B) return;

    __shared__ int sok;
    __shared__ int sidx;
    __shared__ float sd[256];
    __shared__ int   si[256];

    const float rx = recv[3 * r + 0];
    const float ry = recv[3 * r + 1];

    if (t == 0) {
        unsigned long long key = wskey[r];
        unsigned u_idx = (unsigned)(key & 0xFFFFFFFFull);
        unsigned dbits = (unsigned)(key >> 32);
        int ok = 0;
        if (u_idx < (unsigned)L) {
            float2 p = mesh[u_idx];
            float dx = p.x - rx;
            float dy = p.y - ry;
            float d2 = __fadd_rn(__fmul_rn(dx, dx), __fmul_rn(dy, dy));
            if (__float_as_uint(d2) == dbits && d2 < GATE) ok = 1;
        }
        sok = ok;
        sidx = (int)u_idx;
    }
    __syncthreads();

    int idx;
    if (sok) {
        idx = sidx;
    } else {
        // exact brute force for this receiver (correctness backstop)
        float bd2 = INFINITY;
        int bidx = 0x7fffffff;
        for (int j = t; j < L; j += 256) {
            float2 p = mesh[j];
            float dx = p.x - rx;
            float dy = p.y - ry;
            float d2 = __fadd_rn(__fmul_rn(dx, dx), __fmul_rn(dy, dy));
            if (d2 < bd2 || (d2 == bd2 && j < bidx)) { bd2 = d2; bidx = j; }
        }
        sd[t] = bd2;
        si[t] = bidx;
        __syncthreads();
        for (int s = 128; s > 0; s >>= 1) {
            if (t < s) {
                float d2 = sd[t + s];
                int   i  = si[t + s];
                if (d2 < sd[t] || (d2 == sd[t] && i < si[t])) { sd[t] = d2; si[t] = i; }
            }
            __syncthreads();
        }
        idx = si[0];
    }

    if (t == 0) {
        out2[r] = (float)idx;                     // min_index as float
        float2 p = mesh[idx];
        out1[2 * r + 0] = p.x;                    // closest_points
        out1[2 * r + 1] = p.y;
        out0[3 * (size_t)idx + 2] = 1.0f;         // one_hot scatter
        if (r == 0 && B > 1) out0[2] = 1.0f;      // reference's one_hot[0]=1
    }
}

// ---------------- brute-force fallback path (verified in R1) ----------------

__global__ void copy_xy_kernel(const float2* __restrict__ mesh,
                               float* __restrict__ out0, int L) {
    int i = blockIdx.x * blockDim.x + threadIdx.x;
    if (i < L) {
        float2 p = mesh[i];
        out0[3 * i + 0] = p.x;
        out0[3 * i + 1] = p.y;
        out0[3 * i + 2] = 0.0f;
    }
}

__global__ void partial_argmin_kernel(const float2* __restrict__ mesh,
                                      const float* __restrict__ recv,
                                      float* __restrict__ pd2,
                                      int* __restrict__ pidx,
                                      int L, int chunk) {
    const int b = threadIdx.x;
    const int c = blockIdx.x;
    const float rx = recv[3 * b + 0];
    const float ry = recv[3 * b + 1];
    int start = c * chunk;
    int end = min(start + chunk, L);

    float best = INFINITY;
    int bidx = 0x7fffffff;
    #pragma unroll 8
    for (int l = start; l < end; ++l) {
        float2 p = mesh[l];
        float dx = p.x - rx;
        float dy = p.y - ry;
        float d2 = __fadd_rn(__fmul_rn(dx, dx), __fmul_rn(dy, dy));
        if (d2 < best) { best = d2; bidx = l; }
    }
    pd2[c * blockDim.x + b] = best;
    pidx[c * blockDim.x + b] = bidx;
}

__global__ void reduce_finalize_kernel(const float2* __restrict__ mesh,
                                       const float* __restrict__ pd2,
                                       const int* __restrict__ pidx,
                                       float* __restrict__ out0,
                                       float* __restrict__ out1,
                                       float* __restrict__ out2,
                                       int B) {
    const int b = blockIdx.x;
    const int t = threadIdx.x;

    float best = INFINITY;
    int bidx = 0x7fffffff;
    for (int c = t; c < NCHUNK; c += blockDim.x) {
        float d2 = pd2[c * B + b];
        int   i  = pidx[c * B + b];
        if (d2 < best || (d2 == best && i < bidx)) { best = d2; bidx = i; }
    }

    __shared__ float sd[256];
    __shared__ int   si[256];
    sd[t] = best;
    si[t] = bidx;
    __syncthreads();
    for (int s = 128; s > 0; s >>= 1) {
        if (t < s) {
            float d2 = sd[t + s];
            int   i  = si[t + s];
            if (d2 < sd[t] || (d2 == sd[t] && i < si[t])) { sd[t] = d2; si[t] = i; }
        }
        __syncthreads();
    }

    if (t == 0) {
        int idx = si[0];
        out2[b] = (float)idx;
        float2 p = mesh[idx];
        out1[2 * b + 0] = p.x;
        out1[2 * b + 1] = p.y;
        out0[3 * (size_t)idx + 2] = 1.0f;
        if (b == 0) out0[2] = 1.0f;
    }
}

extern "C" void kernel_launch(void* const* d_in, const int* in_sizes, int n_in,
                              void* d_out, int out_size, void* d_ws, size_t ws_size,
                              hipStream_t stream) {
    const float* mesh = (const float*)d_in[0];   // (L,2) f32
    const float* recv = (const float*)d_in[1];   // (B,3) f32
    const int L = in_sizes[0] / 2;
    const int B = in_sizes[1] / 3;

    float* out0 = (float*)d_out;
    float* out1 = out0 + (size_t)3 * L;
    float* out2 = out1 + (size_t)2 * B;

    const size_t need = (size_t)B * sizeof(unsigned long long);

    if (ws_size >= need && B >= 1 && B <= 256) {
        unsigned long long* wskey = (unsigned long long*)d_ws;
        const int nt4 = (L + 3) / 4;
        const int nb1 = (nt4 + 255) / 256;

        fused_filter_kernel<<<nb1, 256, 0, stream>>>(
            (const float4*)mesh, (float4*)out0, recv, wskey, L, B, nt4);
        finalize_kernel<<<B, 256, 0, stream>>>(
            (const float2*)mesh, recv, wskey, out0, out1, out2, L, B);
    } else {
        float* pd2  = (float*)d_ws;
        int*   pidx = (int*)((char*)d_ws + sizeof(float) * (size_t)NCHUNK * B);
        const int chunk = (L + NCHUNK - 1) / NCHUNK;

        copy_xy_kernel<<<(L + 255) / 256, 256, 0, stream>>>(
            (const float2*)mesh, out0, L);
        partial_argmin_kernel<<<NCHUNK, B, 0, stream>>>(
            (const float2*)mesh, recv, pd2, pidx, L, chunk);
        reduce_finalize_kernel<<<B, 256, 0, stream>>>(
            (const float2*)mesh, pd2, pidx, out0, out1, out2, B);
    }
}